// Round 14
// baseline (157.295 us; speedup 1.0000x reference)
//
#include <hip/hip_runtime.h>
#include <math.h>

#define NN 102400
#define D 256
#define B 2048
#define SLAB 64   // rows per block in k_slab (4 waves x 16 rows)

typedef __bf16 bf16x8 __attribute__((ext_vector_type(8)));
typedef float f32x4 __attribute__((ext_vector_type(4)));

// K0: seg_start[b] = lower_bound(seg_ids, b); seg_start[B] = NN
__global__ void k_bounds(const int* __restrict__ seg, int* __restrict__ seg_start) {
    int b = blockIdx.x * blockDim.x + threadIdx.x;
    if (b > B) return;
    int lo = 0, hi = NN;
    while (lo < hi) { int mid = (lo + hi) >> 1; if (seg[mid] < b) lo = mid + 1; else hi = mid; }
    seg_start[b] = lo;
}

// K1 (NEW): flat slab-parallel segment sums. 1600 blocks x 4 waves; wave owns a
// CONTIGUOUS 16-row sub-slab (fixed trip count — no data-dependent loop length).
// Fully-coalesced 1KB float4 row streams, 1-deep prefetch; per-run accumulate
// (seg_ids sorted -> wave-uniform run-change branch), atomicAdd flush per run.
// R13 lesson: every per-segment-loop shape was latency-structure-bound at
// ~65-75 us (warm == cold, FETCH~0); this shape is pure streaming.
__global__ __launch_bounds__(256)
void k_slab(const float* __restrict__ ifeat, const int* __restrict__ seg,
            float* __restrict__ anchor_sum) {
    int w = threadIdx.x >> 6, l = threadIdx.x & 63;
    int r0 = blockIdx.x * SLAB + w * 16;
    const float* base = ifeat + (size_t)r0 * D + l * 4;

    int cur = seg[r0];
    float4 acc = make_float4(0.f, 0.f, 0.f, 0.f);
    float4 nxt = *(const float4*)(base);
#pragma unroll 1
    for (int q = 0; q < 16; ++q) {
        float4 v = nxt;
        if (q < 15) nxt = *(const float4*)(base + (size_t)(q + 1) * D);
        int sg = seg[r0 + q];                  // wave-uniform (scalar path)
        if (sg != cur) {                       // run boundary: flush
            float* p = anchor_sum + (size_t)cur * D + l * 4;
            atomicAdd(p + 0, acc.x); atomicAdd(p + 1, acc.y);
            atomicAdd(p + 2, acc.z); atomicAdd(p + 3, acc.w);
            acc = make_float4(0.f, 0.f, 0.f, 0.f);
            cur = sg;
        }
        acc.x += v.x; acc.y += v.y; acc.z += v.z; acc.w += v.w;
    }
    float* p = anchor_sum + (size_t)cur * D + l * 4;
    atomicAdd(p + 0, acc.x); atomicAdd(p + 1, acc.y);
    atomicAdd(p + 2, acc.z); atomicAdd(p + 3, acc.w);
}

// K2: anchor = anchor_sum / count -> out[:,256:512] + LDS; feat_v = anc @ Wv^T + bv.
// 128 blocks x 16 segments.
__global__ void k_featv2(const float* __restrict__ anchor_sum, const int* __restrict__ seg_start,
                         const float* __restrict__ Wv, const float* __restrict__ bv,
                         float* __restrict__ out, float* __restrict__ feat_v) {
    __shared__ float anc[16][D];
    int b0 = blockIdx.x * 16;
    int t = threadIdx.x; // 256, thread = column
#pragma unroll
    for (int r = 0; r < 16; ++r) {
        int b = b0 + r;
        int cnt = seg_start[b + 1] - seg_start[b];
        float inv = 1.0f / (float)(cnt > 0 ? cnt : 1);
        float v = anchor_sum[(size_t)b * D + t] * inv;
        anc[r][t] = v;
        out[(size_t)b * 512 + 256 + t] = v;
    }
    __syncthreads();
    float acc[16];
#pragma unroll
    for (int s = 0; s < 16; ++s) acc[s] = 0.f;
    const float* wrow = Wv + (size_t)t * D;
    for (int k = 0; k < D; k += 4) {
        float4 w = *(const float4*)(wrow + k);
#pragma unroll
        for (int s = 0; s < 16; ++s) {
            acc[s] += anc[s][k] * w.x + anc[s][k + 1] * w.y
                    + anc[s][k + 2] * w.z + anc[s][k + 3] * w.w;
        }
    }
    float bj = bv[t];
#pragma unroll
    for (int s = 0; s < 16; ++s) feat_v[(size_t)(b0 + s) * D + t] = acc[s] + bj;
}

// K3 (MFMA, single-pass full-Wu): UNCHANGED from R12/R13 for attribution.
__global__ __launch_bounds__(1024, 4)
void k_attn_e_mfma(const float* __restrict__ ifeat, const float* __restrict__ Wu,
                   const float* __restrict__ feat_v, const float* __restrict__ we,
                   const int* __restrict__ seg_ids, float* __restrict__ e_out) {
    __shared__ __bf16 Bs[256 * 256];   // 128 KB; row j stride 512 B; byte ^= (j&7)<<4

    int tx = threadIdx.x;
    int lane = tx & 63;
    int w = tx >> 6;                   // 0..15
    int ln15 = lane & 15;
    int lg = lane >> 4;

    {
        int jl = tx >> 2, kh = tx & 3;
        const float* wp = Wu + (size_t)jl * D + kh * 64;
        char* rowp = (char*)Bs + jl * 512;
        int sw = (jl & 7) << 4;
#pragma unroll
        for (int q = 0; q < 8; ++q) {
            float4 b0 = *(const float4*)(wp + q * 8);
            float4 b1 = *(const float4*)(wp + q * 8 + 4);
            bf16x8 v;
            v[0] = (__bf16)b0.x; v[1] = (__bf16)b0.y; v[2] = (__bf16)b0.z; v[3] = (__bf16)b0.w;
            v[4] = (__bf16)b1.x; v[5] = (__bf16)b1.y; v[6] = (__bf16)b1.z; v[7] = (__bf16)b1.w;
            *(bf16x8*)(rowp + ((kh * 128 + q * 16) ^ sw)) = v;
        }
    }
    __syncthreads();

    int swr = (ln15 & 7) << 4;
    int klo = lg * 16;
    const char* bbase = (const char*)Bs + ln15 * 512;
    const float* feph = feat_v + ln15;
    const float* weh  = we + ln15;

    int wgid = blockIdx.x * 16 + w;

    for (int item = wgid; item < NN / 16; item += 4096) {
        int nb = item * 16;
        const float* ap = ifeat + (size_t)(nb + ln15) * D + lg * 8;

        f32x4 a0 = (f32x4){0.f,0.f,0.f,0.f}, a1 = a0, a2 = a0, a3 = a0,
              a4 = a0, a5 = a0, a6 = a0, a7 = a0,
              a8 = a0, a9 = a0, a10 = a0, a11 = a0,
              a12 = a0, a13 = a0, a14 = a0, a15 = a0;

        float4 xc = *(const float4*)(ap);
        float4 yc = *(const float4*)(ap + 4);
        float4 x1 = *(const float4*)(ap + 32);
        float4 y1 = *(const float4*)(ap + 36);
#pragma unroll 1
        for (int ch = 0; ch < 8; ++ch) {
            int nx = ((ch + 2) & 7) * 32;
            float4 x2 = *(const float4*)(ap + nx);
            float4 y2 = *(const float4*)(ap + nx + 4);
            bf16x8 af;
            af[0] = (__bf16)xc.x; af[1] = (__bf16)xc.y; af[2] = (__bf16)xc.z; af[3] = (__bf16)xc.w;
            af[4] = (__bf16)yc.x; af[5] = (__bf16)yc.y; af[6] = (__bf16)yc.z; af[7] = (__bf16)yc.w;
            int kb = (ch * 64 + klo) ^ swr;
            a0  = __builtin_amdgcn_mfma_f32_16x16x32_bf16(af, *(const bf16x8*)(bbase +  0 * 8192 + kb), a0,  0, 0, 0);
            a1  = __builtin_amdgcn_mfma_f32_16x16x32_bf16(af, *(const bf16x8*)(bbase +  1 * 8192 + kb), a1,  0, 0, 0);
            a2  = __builtin_amdgcn_mfma_f32_16x16x32_bf16(af, *(const bf16x8*)(bbase +  2 * 8192 + kb), a2,  0, 0, 0);
            a3  = __builtin_amdgcn_mfma_f32_16x16x32_bf16(af, *(const bf16x8*)(bbase +  3 * 8192 + kb), a3,  0, 0, 0);
            a4  = __builtin_amdgcn_mfma_f32_16x16x32_bf16(af, *(const bf16x8*)(bbase +  4 * 8192 + kb), a4,  0, 0, 0);
            a5  = __builtin_amdgcn_mfma_f32_16x16x32_bf16(af, *(const bf16x8*)(bbase +  5 * 8192 + kb), a5,  0, 0, 0);
            a6  = __builtin_amdgcn_mfma_f32_16x16x32_bf16(af, *(const bf16x8*)(bbase +  6 * 8192 + kb), a6,  0, 0, 0);
            a7  = __builtin_amdgcn_mfma_f32_16x16x32_bf16(af, *(const bf16x8*)(bbase +  7 * 8192 + kb), a7,  0, 0, 0);
            a8  = __builtin_amdgcn_mfma_f32_16x16x32_bf16(af, *(const bf16x8*)(bbase +  8 * 8192 + kb), a8,  0, 0, 0);
            a9  = __builtin_amdgcn_mfma_f32_16x16x32_bf16(af, *(const bf16x8*)(bbase +  9 * 8192 + kb), a9,  0, 0, 0);
            a10 = __builtin_amdgcn_mfma_f32_16x16x32_bf16(af, *(const bf16x8*)(bbase + 10 * 8192 + kb), a10, 0, 0, 0);
            a11 = __builtin_amdgcn_mfma_f32_16x16x32_bf16(af, *(const bf16x8*)(bbase + 11 * 8192 + kb), a11, 0, 0, 0);
            a12 = __builtin_amdgcn_mfma_f32_16x16x32_bf16(af, *(const bf16x8*)(bbase + 12 * 8192 + kb), a12, 0, 0, 0);
            a13 = __builtin_amdgcn_mfma_f32_16x16x32_bf16(af, *(const bf16x8*)(bbase + 13 * 8192 + kb), a13, 0, 0, 0);
            a14 = __builtin_amdgcn_mfma_f32_16x16x32_bf16(af, *(const bf16x8*)(bbase + 14 * 8192 + kb), a14, 0, 0, 0);
            a15 = __builtin_amdgcn_mfma_f32_16x16x32_bf16(af, *(const bf16x8*)(bbase + 15 * 8192 + kb), a15, 0, 0, 0);
            xc = x1; yc = y1; x1 = x2; y1 = y2;
        }

        int r0 = nb + lg * 4;
        const float* fp0 = feph + (size_t)seg_ids[r0 + 0] * D;
        const float* fp1 = feph + (size_t)seg_ids[r0 + 1] * D;
        const float* fp2 = feph + (size_t)seg_ids[r0 + 2] * D;
        const float* fp3 = feph + (size_t)seg_ids[r0 + 3] * D;
        float part0 = 0.f, part1 = 0.f, part2 = 0.f, part3 = 0.f;

#define EPI(AC, CT) { \
    float w_ = weh[(CT) * 16]; \
    part0 += w_ * __builtin_amdgcn_rcpf(1.f + __expf(-(AC[0] + fp0[(CT) * 16]))); \
    part1 += w_ * __builtin_amdgcn_rcpf(1.f + __expf(-(AC[1] + fp1[(CT) * 16]))); \
    part2 += w_ * __builtin_amdgcn_rcpf(1.f + __expf(-(AC[2] + fp2[(CT) * 16]))); \
    part3 += w_ * __builtin_amdgcn_rcpf(1.f + __expf(-(AC[3] + fp3[(CT) * 16]))); }

        EPI(a0, 0)  EPI(a1, 1)  EPI(a2, 2)  EPI(a3, 3)
        EPI(a4, 4)  EPI(a5, 5)  EPI(a6, 6)  EPI(a7, 7)
        EPI(a8, 8)  EPI(a9, 9)  EPI(a10, 10) EPI(a11, 11)
        EPI(a12, 12) EPI(a13, 13) EPI(a14, 14) EPI(a15, 15)
#undef EPI

#pragma unroll
        for (int off = 8; off >= 1; off >>= 1) {
            part0 += __shfl_xor(part0, off, 64);
            part1 += __shfl_xor(part1, off, 64);
            part2 += __shfl_xor(part2, off, 64);
            part3 += __shfl_xor(part3, off, 64);
        }
        if (ln15 == 0) {
            float4 o = make_float4(part0, part1, part2, part3);
            *(float4*)&e_out[r0] = o;
        }
    }
}

// K4: segment softmax + alpha-weighted segment sum -> out[:, 0:256]. UNCHANGED.
__global__ void k_softmax_rst(const float* __restrict__ ifeat, const int* __restrict__ seg_start,
                              const float* __restrict__ e, float* __restrict__ out) {
    int b = blockIdx.x;
    int t = threadIdx.x; // 256
    int w = t >> 6, l = t & 63;
    int s = seg_start[b], en = seg_start[b + 1];
    float m = -1e30f;
    for (int i = s + t; i < en; i += 256) m = fmaxf(m, e[i]);
#pragma unroll
    for (int off = 32; off >= 1; off >>= 1) m = fmaxf(m, __shfl_xor(m, off, 64));
    __shared__ float red[4];
    if ((t & 63) == 0) red[t >> 6] = m;
    __syncthreads();
    float mall = fmaxf(fmaxf(red[0], red[1]), fmaxf(red[2], red[3]));
    float dsum = 0.f;
    for (int i = s + t; i < en; i += 256) dsum += __expf(e[i] - mall);
#pragma unroll
    for (int off = 32; off >= 1; off >>= 1) dsum += __shfl_xor(dsum, off, 64);
    __shared__ float red2[4];
    if ((t & 63) == 0) red2[t >> 6] = dsum;
    __syncthreads();
    float denom = red2[0] + red2[1] + red2[2] + red2[3];
    float invd = (en > s) ? 1.0f / denom : 0.f;

    float4 acc = make_float4(0.f, 0.f, 0.f, 0.f);
    for (int i = s + w; i < en; i += 4) {
        float al = __expf(e[i] - mall) * invd;
        float4 v = *(const float4*)(ifeat + (size_t)i * D + l * 4);
        acc.x += v.x * al; acc.y += v.y * al; acc.z += v.z * al; acc.w += v.w * al;
    }
    __shared__ float red3[4][256];
    *(float4*)&red3[w][l * 4] = acc;
    __syncthreads();
    out[(size_t)b * 512 + t] = (red3[0][t] + red3[1][t]) + (red3[2][t] + red3[3][t]);
}

extern "C" void kernel_launch(void* const* d_in, const int* in_sizes, int n_in,
                              void* d_out, int out_size, void* d_ws, size_t ws_size,
                              hipStream_t stream) {
    const float* ifeat = (const float*)d_in[0];
    const float* Wu    = (const float*)d_in[1];
    const float* Wv    = (const float*)d_in[2];
    const float* bv    = (const float*)d_in[3];
    const float* we    = (const float*)d_in[4];
    const int*   seg   = (const int*)d_in[5];
    float* out = (float*)d_out;

    char* ws = (char*)d_ws;
    int*   seg_start  = (int*)ws;                                       // (B+1) ints
    float* feat_v     = (float*)(ws + 16384);                           // B*D floats (2 MB)
    float* e_buf      = (float*)(ws + 16384 + (size_t)B * D * 4);       // NN floats (400 KB)
    float* anchor_sum = (float*)(ws + 16384 + (size_t)B * D * 4 + 512 * 1024); // B*D floats (2 MB)

    hipMemsetAsync(anchor_sum, 0, (size_t)B * D * 4, stream);
    k_bounds<<<(B + 1 + 255) / 256, 256, 0, stream>>>(seg, seg_start);
    k_slab<<<NN / SLAB, 256, 0, stream>>>(ifeat, seg, anchor_sum);
    k_featv2<<<B / 16, 256, 0, stream>>>(anchor_sum, seg_start, Wv, bv, out, feat_v);
    k_attn_e_mfma<<<256, 1024, 0, stream>>>(ifeat, Wu, feat_v, we, seg, e_buf);
    k_softmax_rst<<<B, 256, 0, stream>>>(ifeat, seg_start, e_buf, out);
}

// Round 15
// 157.250 us; speedup vs baseline: 1.0003x; 1.0003x over previous
//
#include <hip/hip_runtime.h>
#include <math.h>

#define NN 102400
#define D 256
#define B 2048
#define SLAB 64   // rows per block in k_slab (4 waves x 16 rows)

typedef __bf16 bf16x8 __attribute__((ext_vector_type(8)));
typedef float f32x4 __attribute__((ext_vector_type(4)));

// K_zero: zero anchor_sum (B*D floats = 2 MB). 512 blocks x 256 thr x 1 float4.
// R14 lesson: hipMemsetAsync's fill kernel costs ~59 us here regardless of size
// (latency-bound tiny grid); a properly-gridded zero kernel is ~2 us.
__global__ void k_zero(float4* __restrict__ p) {
    p[blockIdx.x * 256 + threadIdx.x] = make_float4(0.f, 0.f, 0.f, 0.f);
}

// K0: seg_start[b] = lower_bound(seg_ids, b); seg_start[B] = NN
__global__ void k_bounds(const int* __restrict__ seg, int* __restrict__ seg_start) {
    int b = blockIdx.x * blockDim.x + threadIdx.x;
    if (b > B) return;
    int lo = 0, hi = NN;
    while (lo < hi) { int mid = (lo + hi) >> 1; if (seg[mid] < b) lo = mid + 1; else hi = mid; }
    seg_start[b] = lo;
}

// K1: flat slab-parallel segment sums. 1600 blocks x 4 waves; wave owns a
// CONTIGUOUS 16-row sub-slab (fixed trip count). Coalesced 1KB float4 rows,
// 1-deep prefetch; per-run accumulate (sorted seg_ids -> wave-uniform branch),
// atomicAdd flush per run. UNCHANGED from R14 for attribution.
__global__ __launch_bounds__(256)
void k_slab(const float* __restrict__ ifeat, const int* __restrict__ seg,
            float* __restrict__ anchor_sum) {
    int w = threadIdx.x >> 6, l = threadIdx.x & 63;
    int r0 = blockIdx.x * SLAB + w * 16;
    const float* base = ifeat + (size_t)r0 * D + l * 4;

    int cur = seg[r0];
    float4 acc = make_float4(0.f, 0.f, 0.f, 0.f);
    float4 nxt = *(const float4*)(base);
#pragma unroll 1
    for (int q = 0; q < 16; ++q) {
        float4 v = nxt;
        if (q < 15) nxt = *(const float4*)(base + (size_t)(q + 1) * D);
        int sg = seg[r0 + q];                  // wave-uniform (scalar path)
        if (sg != cur) {                       // run boundary: flush
            float* p = anchor_sum + (size_t)cur * D + l * 4;
            atomicAdd(p + 0, acc.x); atomicAdd(p + 1, acc.y);
            atomicAdd(p + 2, acc.z); atomicAdd(p + 3, acc.w);
            acc = make_float4(0.f, 0.f, 0.f, 0.f);
            cur = sg;
        }
        acc.x += v.x; acc.y += v.y; acc.z += v.z; acc.w += v.w;
    }
    float* p = anchor_sum + (size_t)cur * D + l * 4;
    atomicAdd(p + 0, acc.x); atomicAdd(p + 1, acc.y);
    atomicAdd(p + 2, acc.z); atomicAdd(p + 3, acc.w);
}

// K2: anchor = anchor_sum / count -> out[:,256:512] + LDS; feat_v = anc @ Wv^T + bv.
__global__ void k_featv2(const float* __restrict__ anchor_sum, const int* __restrict__ seg_start,
                         const float* __restrict__ Wv, const float* __restrict__ bv,
                         float* __restrict__ out, float* __restrict__ feat_v) {
    __shared__ float anc[16][D];
    int b0 = blockIdx.x * 16;
    int t = threadIdx.x; // 256, thread = column
#pragma unroll
    for (int r = 0; r < 16; ++r) {
        int b = b0 + r;
        int cnt = seg_start[b + 1] - seg_start[b];
        float inv = 1.0f / (float)(cnt > 0 ? cnt : 1);
        float v = anchor_sum[(size_t)b * D + t] * inv;
        anc[r][t] = v;
        out[(size_t)b * 512 + 256 + t] = v;
    }
    __syncthreads();
    float acc[16];
#pragma unroll
    for (int s = 0; s < 16; ++s) acc[s] = 0.f;
    const float* wrow = Wv + (size_t)t * D;
    for (int k = 0; k < D; k += 4) {
        float4 w = *(const float4*)(wrow + k);
#pragma unroll
        for (int s = 0; s < 16; ++s) {
            acc[s] += anc[s][k] * w.x + anc[s][k + 1] * w.y
                    + anc[s][k + 2] * w.z + anc[s][k + 3] * w.w;
        }
    }
    float bj = bv[t];
#pragma unroll
    for (int s = 0; s < 16; ++s) feat_v[(size_t)(b0 + s) * D + t] = acc[s] + bj;
}

// K3 (MFMA, single-pass full-Wu): UNCHANGED from R12-R14 for attribution.
__global__ __launch_bounds__(1024, 4)
void k_attn_e_mfma(const float* __restrict__ ifeat, const float* __restrict__ Wu,
                   const float* __restrict__ feat_v, const float* __restrict__ we,
                   const int* __restrict__ seg_ids, float* __restrict__ e_out) {
    __shared__ __bf16 Bs[256 * 256];   // 128 KB; row j stride 512 B; byte ^= (j&7)<<4

    int tx = threadIdx.x;
    int lane = tx & 63;
    int w = tx >> 6;                   // 0..15
    int ln15 = lane & 15;
    int lg = lane >> 4;

    {
        int jl = tx >> 2, kh = tx & 3;
        const float* wp = Wu + (size_t)jl * D + kh * 64;
        char* rowp = (char*)Bs + jl * 512;
        int sw = (jl & 7) << 4;
#pragma unroll
        for (int q = 0; q < 8; ++q) {
            float4 b0 = *(const float4*)(wp + q * 8);
            float4 b1 = *(const float4*)(wp + q * 8 + 4);
            bf16x8 v;
            v[0] = (__bf16)b0.x; v[1] = (__bf16)b0.y; v[2] = (__bf16)b0.z; v[3] = (__bf16)b0.w;
            v[4] = (__bf16)b1.x; v[5] = (__bf16)b1.y; v[6] = (__bf16)b1.z; v[7] = (__bf16)b1.w;
            *(bf16x8*)(rowp + ((kh * 128 + q * 16) ^ sw)) = v;
        }
    }
    __syncthreads();

    int swr = (ln15 & 7) << 4;
    int klo = lg * 16;
    const char* bbase = (const char*)Bs + ln15 * 512;
    const float* feph = feat_v + ln15;
    const float* weh  = we + ln15;

    int wgid = blockIdx.x * 16 + w;

    for (int item = wgid; item < NN / 16; item += 4096) {
        int nb = item * 16;
        const float* ap = ifeat + (size_t)(nb + ln15) * D + lg * 8;

        f32x4 a0 = (f32x4){0.f,0.f,0.f,0.f}, a1 = a0, a2 = a0, a3 = a0,
              a4 = a0, a5 = a0, a6 = a0, a7 = a0,
              a8 = a0, a9 = a0, a10 = a0, a11 = a0,
              a12 = a0, a13 = a0, a14 = a0, a15 = a0;

        float4 xc = *(const float4*)(ap);
        float4 yc = *(const float4*)(ap + 4);
        float4 x1 = *(const float4*)(ap + 32);
        float4 y1 = *(const float4*)(ap + 36);
#pragma unroll 1
        for (int ch = 0; ch < 8; ++ch) {
            int nx = ((ch + 2) & 7) * 32;
            float4 x2 = *(const float4*)(ap + nx);
            float4 y2 = *(const float4*)(ap + nx + 4);
            bf16x8 af;
            af[0] = (__bf16)xc.x; af[1] = (__bf16)xc.y; af[2] = (__bf16)xc.z; af[3] = (__bf16)xc.w;
            af[4] = (__bf16)yc.x; af[5] = (__bf16)yc.y; af[6] = (__bf16)yc.z; af[7] = (__bf16)yc.w;
            int kb = (ch * 64 + klo) ^ swr;
            a0  = __builtin_amdgcn_mfma_f32_16x16x32_bf16(af, *(const bf16x8*)(bbase +  0 * 8192 + kb), a0,  0, 0, 0);
            a1  = __builtin_amdgcn_mfma_f32_16x16x32_bf16(af, *(const bf16x8*)(bbase +  1 * 8192 + kb), a1,  0, 0, 0);
            a2  = __builtin_amdgcn_mfma_f32_16x16x32_bf16(af, *(const bf16x8*)(bbase +  2 * 8192 + kb), a2,  0, 0, 0);
            a3  = __builtin_amdgcn_mfma_f32_16x16x32_bf16(af, *(const bf16x8*)(bbase +  3 * 8192 + kb), a3,  0, 0, 0);
            a4  = __builtin_amdgcn_mfma_f32_16x16x32_bf16(af, *(const bf16x8*)(bbase +  4 * 8192 + kb), a4,  0, 0, 0);
            a5  = __builtin_amdgcn_mfma_f32_16x16x32_bf16(af, *(const bf16x8*)(bbase +  5 * 8192 + kb), a5,  0, 0, 0);
            a6  = __builtin_amdgcn_mfma_f32_16x16x32_bf16(af, *(const bf16x8*)(bbase +  6 * 8192 + kb), a6,  0, 0, 0);
            a7  = __builtin_amdgcn_mfma_f32_16x16x32_bf16(af, *(const bf16x8*)(bbase +  7 * 8192 + kb), a7,  0, 0, 0);
            a8  = __builtin_amdgcn_mfma_f32_16x16x32_bf16(af, *(const bf16x8*)(bbase +  8 * 8192 + kb), a8,  0, 0, 0);
            a9  = __builtin_amdgcn_mfma_f32_16x16x32_bf16(af, *(const bf16x8*)(bbase +  9 * 8192 + kb), a9,  0, 0, 0);
            a10 = __builtin_amdgcn_mfma_f32_16x16x32_bf16(af, *(const bf16x8*)(bbase + 10 * 8192 + kb), a10, 0, 0, 0);
            a11 = __builtin_amdgcn_mfma_f32_16x16x32_bf16(af, *(const bf16x8*)(bbase + 11 * 8192 + kb), a11, 0, 0, 0);
            a12 = __builtin_amdgcn_mfma_f32_16x16x32_bf16(af, *(const bf16x8*)(bbase + 12 * 8192 + kb), a12, 0, 0, 0);
            a13 = __builtin_amdgcn_mfma_f32_16x16x32_bf16(af, *(const bf16x8*)(bbase + 13 * 8192 + kb), a13, 0, 0, 0);
            a14 = __builtin_amdgcn_mfma_f32_16x16x32_bf16(af, *(const bf16x8*)(bbase + 14 * 8192 + kb), a14, 0, 0, 0);
            a15 = __builtin_amdgcn_mfma_f32_16x16x32_bf16(af, *(const bf16x8*)(bbase + 15 * 8192 + kb), a15, 0, 0, 0);
            xc = x1; yc = y1; x1 = x2; y1 = y2;
        }

        int r0 = nb + lg * 4;
        const float* fp0 = feph + (size_t)seg_ids[r0 + 0] * D;
        const float* fp1 = feph + (size_t)seg_ids[r0 + 1] * D;
        const float* fp2 = feph + (size_t)seg_ids[r0 + 2] * D;
        const float* fp3 = feph + (size_t)seg_ids[r0 + 3] * D;
        float part0 = 0.f, part1 = 0.f, part2 = 0.f, part3 = 0.f;

#define EPI(AC, CT) { \
    float w_ = weh[(CT) * 16]; \
    part0 += w_ * __builtin_amdgcn_rcpf(1.f + __expf(-(AC[0] + fp0[(CT) * 16]))); \
    part1 += w_ * __builtin_amdgcn_rcpf(1.f + __expf(-(AC[1] + fp1[(CT) * 16]))); \
    part2 += w_ * __builtin_amdgcn_rcpf(1.f + __expf(-(AC[2] + fp2[(CT) * 16]))); \
    part3 += w_ * __builtin_amdgcn_rcpf(1.f + __expf(-(AC[3] + fp3[(CT) * 16]))); }

        EPI(a0, 0)  EPI(a1, 1)  EPI(a2, 2)  EPI(a3, 3)
        EPI(a4, 4)  EPI(a5, 5)  EPI(a6, 6)  EPI(a7, 7)
        EPI(a8, 8)  EPI(a9, 9)  EPI(a10, 10) EPI(a11, 11)
        EPI(a12, 12) EPI(a13, 13) EPI(a14, 14) EPI(a15, 15)
#undef EPI

#pragma unroll
        for (int off = 8; off >= 1; off >>= 1) {
            part0 += __shfl_xor(part0, off, 64);
            part1 += __shfl_xor(part1, off, 64);
            part2 += __shfl_xor(part2, off, 64);
            part3 += __shfl_xor(part3, off, 64);
        }
        if (ln15 == 0) {
            float4 o = make_float4(part0, part1, part2, part3);
            *(float4*)&e_out[r0] = o;
        }
    }
}

// K4: segment softmax + alpha-weighted segment sum -> out[:, 0:256]. UNCHANGED.
__global__ void k_softmax_rst(const float* __restrict__ ifeat, const int* __restrict__ seg_start,
                              const float* __restrict__ e, float* __restrict__ out) {
    int b = blockIdx.x;
    int t = threadIdx.x; // 256
    int w = t >> 6, l = t & 63;
    int s = seg_start[b], en = seg_start[b + 1];
    float m = -1e30f;
    for (int i = s + t; i < en; i += 256) m = fmaxf(m, e[i]);
#pragma unroll
    for (int off = 32; off >= 1; off >>= 1) m = fmaxf(m, __shfl_xor(m, off, 64));
    __shared__ float red[4];
    if ((t & 63) == 0) red[t >> 6] = m;
    __syncthreads();
    float mall = fmaxf(fmaxf(red[0], red[1]), fmaxf(red[2], red[3]));
    float dsum = 0.f;
    for (int i = s + t; i < en; i += 256) dsum += __expf(e[i] - mall);
#pragma unroll
    for (int off = 32; off >= 1; off >>= 1) dsum += __shfl_xor(dsum, off, 64);
    __shared__ float red2[4];
    if ((t & 63) == 0) red2[t >> 6] = dsum;
    __syncthreads();
    float denom = red2[0] + red2[1] + red2[2] + red2[3];
    float invd = (en > s) ? 1.0f / denom : 0.f;

    float4 acc = make_float4(0.f, 0.f, 0.f, 0.f);
    for (int i = s + w; i < en; i += 4) {
        float al = __expf(e[i] - mall) * invd;
        float4 v = *(const float4*)(ifeat + (size_t)i * D + l * 4);
        acc.x += v.x * al; acc.y += v.y * al; acc.z += v.z * al; acc.w += v.w * al;
    }
    __shared__ float red3[4][256];
    *(float4*)&red3[w][l * 4] = acc;
    __syncthreads();
    out[(size_t)b * 512 + t] = (red3[0][t] + red3[1][t]) + (red3[2][t] + red3[3][t]);
}

extern "C" void kernel_launch(void* const* d_in, const int* in_sizes, int n_in,
                              void* d_out, int out_size, void* d_ws, size_t ws_size,
                              hipStream_t stream) {
    const float* ifeat = (const float*)d_in[0];
    const float* Wu    = (const float*)d_in[1];
    const float* Wv    = (const float*)d_in[2];
    const float* bv    = (const float*)d_in[3];
    const float* we    = (const float*)d_in[4];
    const int*   seg   = (const int*)d_in[5];
    float* out = (float*)d_out;

    char* ws = (char*)d_ws;
    int*   seg_start  = (int*)ws;                                       // (B+1) ints
    float* feat_v     = (float*)(ws + 16384);                           // B*D floats (2 MB)
    float* e_buf      = (float*)(ws + 16384 + (size_t)B * D * 4);       // NN floats (400 KB)
    float* anchor_sum = (float*)(ws + 16384 + (size_t)B * D * 4 + 512 * 1024); // B*D floats (2 MB)

    k_zero<<<512, 256, 0, stream>>>((float4*)anchor_sum);
    k_bounds<<<(B + 1 + 255) / 256, 256, 0, stream>>>(seg, seg_start);
    k_slab<<<NN / SLAB, 256, 0, stream>>>(ifeat, seg, anchor_sum);
    k_featv2<<<B / 16, 256, 0, stream>>>(anchor_sum, seg_start, Wv, bv, out, feat_v);
    k_attn_e_mfma<<<256, 1024, 0, stream>>>(ifeat, Wu, feat_v, we, seg, e_buf);
    k_softmax_rst<<<B, 256, 0, stream>>>(ifeat, seg_start, e_buf, out);
}

// Round 16
// 110.109 us; speedup vs baseline: 1.4285x; 1.4281x over previous
//
#include <hip/hip_runtime.h>
#include <math.h>

#define NN 102400
#define D 256
#define B 2048

typedef __bf16 bf16x8 __attribute__((ext_vector_type(8)));
typedef float f32x4 __attribute__((ext_vector_type(4)));

// K_prep: fused bounds + anchor + feat_v (R12 structure — best known, 109.8 total).
// R16 change: anchor phase 2-row -> 6-row unroll. R12 profile showed k_prep 63.8us
// at 11% HBM, 9% VALU, warm==cold: in-flight-byte starvation (2KB/wave). 6-row =
// 6KB/wave (12MB chip-wide > ~5.7MB latency-BW product) and 3x shorter wait chain.
__global__ __launch_bounds__(256)
void k_prep(const float* __restrict__ ifeat, const int* __restrict__ seg,
            const float* __restrict__ Wv, const float* __restrict__ bv,
            float* __restrict__ out, int* __restrict__ seg_start,
            float* __restrict__ feat_v) {
    __shared__ float anc[4][D];
    __shared__ int sb[5];
    int p = blockIdx.x, t = threadIdx.x;
    int b0 = p * 4;
    if (t < 5) {
        int target = b0 + t;
        int lo = 0, hi = NN;
        while (lo < hi) { int mid = (lo + hi) >> 1; if (seg[mid] < target) lo = mid + 1; else hi = mid; }
        sb[t] = lo;
        seg_start[target] = lo;   // overlapping writes store identical values
    }
    __syncthreads();
    int w = t >> 6, l = t & 63;
    {
        int s = sb[w], e = sb[w + 1];
        float4 a0 = make_float4(0.f, 0.f, 0.f, 0.f), a1 = a0, a2 = a0, a3 = a0, a4 = a0, a5 = a0;
        const float* bp = ifeat + (size_t)l * 4;
        int i = s;
        for (; i + 5 < e; i += 6) {   // 6 rows, 6 KB/wave in flight
            float4 v0 = *(const float4*)(bp + (size_t)(i + 0) * D);
            float4 v1 = *(const float4*)(bp + (size_t)(i + 1) * D);
            float4 v2 = *(const float4*)(bp + (size_t)(i + 2) * D);
            float4 v3 = *(const float4*)(bp + (size_t)(i + 3) * D);
            float4 v4 = *(const float4*)(bp + (size_t)(i + 4) * D);
            float4 v5 = *(const float4*)(bp + (size_t)(i + 5) * D);
            a0.x += v0.x; a0.y += v0.y; a0.z += v0.z; a0.w += v0.w;
            a1.x += v1.x; a1.y += v1.y; a1.z += v1.z; a1.w += v1.w;
            a2.x += v2.x; a2.y += v2.y; a2.z += v2.z; a2.w += v2.w;
            a3.x += v3.x; a3.y += v3.y; a3.z += v3.z; a3.w += v3.w;
            a4.x += v4.x; a4.y += v4.y; a4.z += v4.z; a4.w += v4.w;
            a5.x += v5.x; a5.y += v5.y; a5.z += v5.z; a5.w += v5.w;
        }
        for (; i < e; ++i) {
            float4 v0 = *(const float4*)(bp + (size_t)i * D);
            a0.x += v0.x; a0.y += v0.y; a0.z += v0.z; a0.w += v0.w;
        }
        int cnt = e - s;
        float inv = 1.0f / (float)(cnt > 0 ? cnt : 1);
        float4 sm = make_float4(((a0.x + a1.x) + (a2.x + a3.x)) + (a4.x + a5.x),
                                ((a0.y + a1.y) + (a2.y + a3.y)) + (a4.y + a5.y),
                                ((a0.z + a1.z) + (a2.z + a3.z)) + (a4.z + a5.z),
                                ((a0.w + a1.w) + (a2.w + a3.w)) + (a4.w + a5.w));
        sm.x *= inv; sm.y *= inv; sm.z *= inv; sm.w *= inv;
        *(float4*)&anc[w][l * 4] = sm;
        *(float4*)(out + (size_t)(b0 + w) * 512 + 256 + l * 4) = sm;
    }
    __syncthreads();
    // feat_v: thread = output col t
    float a0 = 0.f, a1 = 0.f, a2 = 0.f, a3 = 0.f;
    const float* wrow = Wv + (size_t)t * D;
    for (int k = 0; k < D; k += 4) {
        float4 wv = *(const float4*)(wrow + k);
        a0 += anc[0][k] * wv.x + anc[0][k + 1] * wv.y + anc[0][k + 2] * wv.z + anc[0][k + 3] * wv.w;
        a1 += anc[1][k] * wv.x + anc[1][k + 1] * wv.y + anc[1][k + 2] * wv.z + anc[1][k + 3] * wv.w;
        a2 += anc[2][k] * wv.x + anc[2][k + 1] * wv.y + anc[2][k + 2] * wv.z + anc[2][k + 3] * wv.w;
        a3 += anc[3][k] * wv.x + anc[3][k + 1] * wv.y + anc[3][k + 2] * wv.z + anc[3][k + 3] * wv.w;
    }
    float bj = bv[t];
    feat_v[(size_t)(b0 + 0) * D + t] = a0 + bj;
    feat_v[(size_t)(b0 + 1) * D + t] = a1 + bj;
    feat_v[(size_t)(b0 + 2) * D + t] = a2 + bj;
    feat_v[(size_t)(b0 + 3) * D + t] = a3 + bj;
}

// K3 (MFMA, single-pass full-Wu): UNCHANGED from R12 (best-known config).
__global__ __launch_bounds__(1024, 4)
void k_attn_e_mfma(const float* __restrict__ ifeat, const float* __restrict__ Wu,
                   const float* __restrict__ feat_v, const float* __restrict__ we,
                   const int* __restrict__ seg_ids, float* __restrict__ e_out) {
    __shared__ __bf16 Bs[256 * 256];   // 128 KB; row j stride 512 B; byte ^= (j&7)<<4

    int tx = threadIdx.x;
    int lane = tx & 63;
    int w = tx >> 6;                   // 0..15
    int ln15 = lane & 15;
    int lg = lane >> 4;

    {
        int jl = tx >> 2, kh = tx & 3;
        const float* wp = Wu + (size_t)jl * D + kh * 64;
        char* rowp = (char*)Bs + jl * 512;
        int sw = (jl & 7) << 4;
#pragma unroll
        for (int q = 0; q < 8; ++q) {
            float4 b0 = *(const float4*)(wp + q * 8);
            float4 b1 = *(const float4*)(wp + q * 8 + 4);
            bf16x8 v;
            v[0] = (__bf16)b0.x; v[1] = (__bf16)b0.y; v[2] = (__bf16)b0.z; v[3] = (__bf16)b0.w;
            v[4] = (__bf16)b1.x; v[5] = (__bf16)b1.y; v[6] = (__bf16)b1.z; v[7] = (__bf16)b1.w;
            *(bf16x8*)(rowp + ((kh * 128 + q * 16) ^ sw)) = v;
        }
    }
    __syncthreads();

    int swr = (ln15 & 7) << 4;
    int klo = lg * 16;
    const char* bbase = (const char*)Bs + ln15 * 512;
    const float* feph = feat_v + ln15;
    const float* weh  = we + ln15;

    int wgid = blockIdx.x * 16 + w;

    for (int item = wgid; item < NN / 16; item += 4096) {
        int nb = item * 16;
        const float* ap = ifeat + (size_t)(nb + ln15) * D + lg * 8;

        f32x4 a0 = (f32x4){0.f,0.f,0.f,0.f}, a1 = a0, a2 = a0, a3 = a0,
              a4 = a0, a5 = a0, a6 = a0, a7 = a0,
              a8 = a0, a9 = a0, a10 = a0, a11 = a0,
              a12 = a0, a13 = a0, a14 = a0, a15 = a0;

        float4 xc = *(const float4*)(ap);
        float4 yc = *(const float4*)(ap + 4);
        float4 x1 = *(const float4*)(ap + 32);
        float4 y1 = *(const float4*)(ap + 36);
#pragma unroll 1
        for (int ch = 0; ch < 8; ++ch) {
            int nx = ((ch + 2) & 7) * 32;
            float4 x2 = *(const float4*)(ap + nx);
            float4 y2 = *(const float4*)(ap + nx + 4);
            bf16x8 af;
            af[0] = (__bf16)xc.x; af[1] = (__bf16)xc.y; af[2] = (__bf16)xc.z; af[3] = (__bf16)xc.w;
            af[4] = (__bf16)yc.x; af[5] = (__bf16)yc.y; af[6] = (__bf16)yc.z; af[7] = (__bf16)yc.w;
            int kb = (ch * 64 + klo) ^ swr;
            a0  = __builtin_amdgcn_mfma_f32_16x16x32_bf16(af, *(const bf16x8*)(bbase +  0 * 8192 + kb), a0,  0, 0, 0);
            a1  = __builtin_amdgcn_mfma_f32_16x16x32_bf16(af, *(const bf16x8*)(bbase +  1 * 8192 + kb), a1,  0, 0, 0);
            a2  = __builtin_amdgcn_mfma_f32_16x16x32_bf16(af, *(const bf16x8*)(bbase +  2 * 8192 + kb), a2,  0, 0, 0);
            a3  = __builtin_amdgcn_mfma_f32_16x16x32_bf16(af, *(const bf16x8*)(bbase +  3 * 8192 + kb), a3,  0, 0, 0);
            a4  = __builtin_amdgcn_mfma_f32_16x16x32_bf16(af, *(const bf16x8*)(bbase +  4 * 8192 + kb), a4,  0, 0, 0);
            a5  = __builtin_amdgcn_mfma_f32_16x16x32_bf16(af, *(const bf16x8*)(bbase +  5 * 8192 + kb), a5,  0, 0, 0);
            a6  = __builtin_amdgcn_mfma_f32_16x16x32_bf16(af, *(const bf16x8*)(bbase +  6 * 8192 + kb), a6,  0, 0, 0);
            a7  = __builtin_amdgcn_mfma_f32_16x16x32_bf16(af, *(const bf16x8*)(bbase +  7 * 8192 + kb), a7,  0, 0, 0);
            a8  = __builtin_amdgcn_mfma_f32_16x16x32_bf16(af, *(const bf16x8*)(bbase +  8 * 8192 + kb), a8,  0, 0, 0);
            a9  = __builtin_amdgcn_mfma_f32_16x16x32_bf16(af, *(const bf16x8*)(bbase +  9 * 8192 + kb), a9,  0, 0, 0);
            a10 = __builtin_amdgcn_mfma_f32_16x16x32_bf16(af, *(const bf16x8*)(bbase + 10 * 8192 + kb), a10, 0, 0, 0);
            a11 = __builtin_amdgcn_mfma_f32_16x16x32_bf16(af, *(const bf16x8*)(bbase + 11 * 8192 + kb), a11, 0, 0, 0);
            a12 = __builtin_amdgcn_mfma_f32_16x16x32_bf16(af, *(const bf16x8*)(bbase + 12 * 8192 + kb), a12, 0, 0, 0);
            a13 = __builtin_amdgcn_mfma_f32_16x16x32_bf16(af, *(const bf16x8*)(bbase + 13 * 8192 + kb), a13, 0, 0, 0);
            a14 = __builtin_amdgcn_mfma_f32_16x16x32_bf16(af, *(const bf16x8*)(bbase + 14 * 8192 + kb), a14, 0, 0, 0);
            a15 = __builtin_amdgcn_mfma_f32_16x16x32_bf16(af, *(const bf16x8*)(bbase + 15 * 8192 + kb), a15, 0, 0, 0);
            xc = x1; yc = y1; x1 = x2; y1 = y2;
        }

        int r0 = nb + lg * 4;
        const float* fp0 = feph + (size_t)seg_ids[r0 + 0] * D;
        const float* fp1 = feph + (size_t)seg_ids[r0 + 1] * D;
        const float* fp2 = feph + (size_t)seg_ids[r0 + 2] * D;
        const float* fp3 = feph + (size_t)seg_ids[r0 + 3] * D;
        float part0 = 0.f, part1 = 0.f, part2 = 0.f, part3 = 0.f;

#define EPI(AC, CT) { \
    float w_ = weh[(CT) * 16]; \
    part0 += w_ * __builtin_amdgcn_rcpf(1.f + __expf(-(AC[0] + fp0[(CT) * 16]))); \
    part1 += w_ * __builtin_amdgcn_rcpf(1.f + __expf(-(AC[1] + fp1[(CT) * 16]))); \
    part2 += w_ * __builtin_amdgcn_rcpf(1.f + __expf(-(AC[2] + fp2[(CT) * 16]))); \
    part3 += w_ * __builtin_amdgcn_rcpf(1.f + __expf(-(AC[3] + fp3[(CT) * 16]))); }

        EPI(a0, 0)  EPI(a1, 1)  EPI(a2, 2)  EPI(a3, 3)
        EPI(a4, 4)  EPI(a5, 5)  EPI(a6, 6)  EPI(a7, 7)
        EPI(a8, 8)  EPI(a9, 9)  EPI(a10, 10) EPI(a11, 11)
        EPI(a12, 12) EPI(a13, 13) EPI(a14, 14) EPI(a15, 15)
#undef EPI

#pragma unroll
        for (int off = 8; off >= 1; off >>= 1) {
            part0 += __shfl_xor(part0, off, 64);
            part1 += __shfl_xor(part1, off, 64);
            part2 += __shfl_xor(part2, off, 64);
            part3 += __shfl_xor(part3, off, 64);
        }
        if (ln15 == 0) {
            float4 o = make_float4(part0, part1, part2, part3);
            *(float4*)&e_out[r0] = o;
        }
    }
}

// K4: segment softmax + alpha-weighted segment sum -> out[:, 0:256]. UNCHANGED from R12.
__global__ void k_softmax_rst(const float* __restrict__ ifeat, const int* __restrict__ seg_start,
                              const float* __restrict__ e, float* __restrict__ out) {
    int b = blockIdx.x;
    int t = threadIdx.x; // 256
    int w = t >> 6, l = t & 63;
    int s = seg_start[b], en = seg_start[b + 1];
    float m = -1e30f;
    for (int i = s + t; i < en; i += 256) m = fmaxf(m, e[i]);
#pragma unroll
    for (int off = 32; off >= 1; off >>= 1) m = fmaxf(m, __shfl_xor(m, off, 64));
    __shared__ float red[4];
    if ((t & 63) == 0) red[t >> 6] = m;
    __syncthreads();
    float mall = fmaxf(fmaxf(red[0], red[1]), fmaxf(red[2], red[3]));
    float dsum = 0.f;
    for (int i = s + t; i < en; i += 256) dsum += __expf(e[i] - mall);
#pragma unroll
    for (int off = 32; off >= 1; off >>= 1) dsum += __shfl_xor(dsum, off, 64);
    __shared__ float red2[4];
    if ((t & 63) == 0) red2[t >> 6] = dsum;
    __syncthreads();
    float denom = red2[0] + red2[1] + red2[2] + red2[3];
    float invd = (en > s) ? 1.0f / denom : 0.f;

    float4 acc = make_float4(0.f, 0.f, 0.f, 0.f);
    for (int i = s + w; i < en; i += 4) {
        float al = __expf(e[i] - mall) * invd;
        float4 v = *(const float4*)(ifeat + (size_t)i * D + l * 4);
        acc.x += v.x * al; acc.y += v.y * al; acc.z += v.z * al; acc.w += v.w * al;
    }
    __shared__ float red3[4][256];
    *(float4*)&red3[w][l * 4] = acc;
    __syncthreads();
    out[(size_t)b * 512 + t] = (red3[0][t] + red3[1][t]) + (red3[2][t] + red3[3][t]);
}

extern "C" void kernel_launch(void* const* d_in, const int* in_sizes, int n_in,
                              void* d_out, int out_size, void* d_ws, size_t ws_size,
                              hipStream_t stream) {
    const float* ifeat = (const float*)d_in[0];
    const float* Wu    = (const float*)d_in[1];
    const float* Wv    = (const float*)d_in[2];
    const float* bv    = (const float*)d_in[3];
    const float* we    = (const float*)d_in[4];
    const int*   seg   = (const int*)d_in[5];
    float* out = (float*)d_out;

    char* ws = (char*)d_ws;
    int*   seg_start = (int*)ws;                                   // (B+1) ints
    float* feat_v    = (float*)(ws + 16384);                       // B*D floats (2 MB)
    float* e_buf     = (float*)(ws + 16384 + (size_t)B * D * 4);   // NN floats (400 KB)

    k_prep<<<B / 4, 256, 0, stream>>>(ifeat, seg, Wv, bv, out, seg_start, feat_v);
    k_attn_e_mfma<<<256, 1024, 0, stream>>>(ifeat, Wu, feat_v, we, seg, e_buf);
    k_softmax_rst<<<B, 256, 0, stream>>>(ifeat, seg_start, e_buf, out);
}

// Round 17
// 107.552 us; speedup vs baseline: 1.4625x; 1.0238x over previous
//
#include <hip/hip_runtime.h>
#include <math.h>

#define NN 102400
#define D 256
#define B 2048

typedef __bf16 bf16x8 __attribute__((ext_vector_type(8)));
typedef float f32x4 __attribute__((ext_vector_type(4)));

// K0: seg_start[b] = lower_bound(seg_ids, b); seg_start[B] = NN
__global__ void k_bounds(const int* __restrict__ seg, int* __restrict__ seg_start) {
    int b = blockIdx.x * blockDim.x + threadIdx.x;
    if (b > B) return;
    int lo = 0, hi = NN;
    while (lo < hi) { int mid = (lo + hi) >> 1; if (seg[mid] < b) lo = mid + 1; else hi = mid; }
    seg_start[b] = lo;
}

// K1 (R17): anchor, block-per-segment. 2048 blocks x 4 waves (8 blocks/CU —
// backfill smooths ragged segment lengths, unlike R12's exactly-2/CU). Wave w
// takes rows s+w stride 4, 6-row batches (24KB/block in flight). LDS reduce.
// Writes anchor to out[:,256:512] AND dense anc_buf for featv3's staging.
__global__ __launch_bounds__(256)
void k_anchor3(const float* __restrict__ ifeat, const int* __restrict__ seg_start,
               float* __restrict__ out, float* __restrict__ anc_buf) {
    int b = blockIdx.x;
    int t = threadIdx.x;
    int w = t >> 6, l = t & 63;
    int s = seg_start[b], e = seg_start[b + 1];
    const float* bp = ifeat + (size_t)l * 4;
    float4 a0 = make_float4(0.f, 0.f, 0.f, 0.f), a1 = a0, a2 = a0, a3 = a0, a4 = a0, a5 = a0;
    int i = s + w;
    for (; i + 20 < e; i += 24) {   // 6 strided rows per batch per wave
        float4 v0 = *(const float4*)(bp + (size_t)(i +  0) * D);
        float4 v1 = *(const float4*)(bp + (size_t)(i +  4) * D);
        float4 v2 = *(const float4*)(bp + (size_t)(i +  8) * D);
        float4 v3 = *(const float4*)(bp + (size_t)(i + 12) * D);
        float4 v4 = *(const float4*)(bp + (size_t)(i + 16) * D);
        float4 v5 = *(const float4*)(bp + (size_t)(i + 20) * D);
        a0.x += v0.x; a0.y += v0.y; a0.z += v0.z; a0.w += v0.w;
        a1.x += v1.x; a1.y += v1.y; a1.z += v1.z; a1.w += v1.w;
        a2.x += v2.x; a2.y += v2.y; a2.z += v2.z; a2.w += v2.w;
        a3.x += v3.x; a3.y += v3.y; a3.z += v3.z; a3.w += v3.w;
        a4.x += v4.x; a4.y += v4.y; a4.z += v4.z; a4.w += v4.w;
        a5.x += v5.x; a5.y += v5.y; a5.z += v5.z; a5.w += v5.w;
    }
    for (; i < e; i += 4) {
        float4 v = *(const float4*)(bp + (size_t)i * D);
        a0.x += v.x; a0.y += v.y; a0.z += v.z; a0.w += v.w;
    }
    float4 acc = make_float4(((a0.x + a1.x) + (a2.x + a3.x)) + (a4.x + a5.x),
                             ((a0.y + a1.y) + (a2.y + a3.y)) + (a4.y + a5.y),
                             ((a0.z + a1.z) + (a2.z + a3.z)) + (a4.z + a5.z),
                             ((a0.w + a1.w) + (a2.w + a3.w)) + (a4.w + a5.w));
    __shared__ float red[4][256];
    *(float4*)&red[w][l * 4] = acc;
    __syncthreads();
    float sum = (red[0][t] + red[1][t]) + (red[2][t] + red[3][t]);
    int cnt = e - s;
    float inv = 1.0f / (float)(cnt > 0 ? cnt : 1);
    float v = sum * inv;
    out[(size_t)b * 512 + 256 + t] = v;
    anc_buf[(size_t)b * D + t] = v;
}

// K2 (R17, MFMA): feat_v = anc @ Wv^T + bv as a 2048x256x256 bf16 GEMM.
// 128 blocks x 16 segments. A = anc bf16 in padded LDS; B-frags read Wv
// ROW-MAJOR COALESCED direct from global (R16 lesson: thread-per-column Wv
// reads were 64 lines/instr, L1-defeating — the hidden ~15us in k_prep).
__global__ __launch_bounds__(256)
void k_featv3(const float* __restrict__ anc_buf, const float* __restrict__ Wv,
              const float* __restrict__ bv, float* __restrict__ feat_v) {
    __shared__ __bf16 As[16][264];   // 256 + 8 pad
    int b0 = blockIdx.x * 16;
    int t = threadIdx.x;
    int lane = t & 63, w = t >> 6;
    int ln15 = lane & 15, lg = lane >> 4;
#pragma unroll
    for (int r = 0; r < 16; ++r) As[r][t] = (__bf16)anc_buf[(size_t)(b0 + r) * D + t];
    __syncthreads();
    bf16x8 afr[8];
#pragma unroll
    for (int kc = 0; kc < 8; ++kc) afr[kc] = *(const bf16x8*)&As[ln15][kc * 32 + lg * 8];
#pragma unroll
    for (int q = 0; q < 4; ++q) {
        int jt = w * 4 + q;                  // 16 j-tiles over 4 waves
        f32x4 acc = (f32x4){0.f, 0.f, 0.f, 0.f};
#pragma unroll
        for (int kc = 0; kc < 8; ++kc) {
            const float* wp = Wv + (size_t)(jt * 16 + ln15) * D + kc * 32 + lg * 8;
            float4 p = *(const float4*)(wp);
            float4 r4 = *(const float4*)(wp + 4);
            bf16x8 bfr;
            bfr[0] = (__bf16)p.x;  bfr[1] = (__bf16)p.y;  bfr[2] = (__bf16)p.z;  bfr[3] = (__bf16)p.w;
            bfr[4] = (__bf16)r4.x; bfr[5] = (__bf16)r4.y; bfr[6] = (__bf16)r4.z; bfr[7] = (__bf16)r4.w;
            acc = __builtin_amdgcn_mfma_f32_16x16x32_bf16(afr[kc], bfr, acc, 0, 0, 0);
        }
        float bvj = bv[jt * 16 + ln15];
#pragma unroll
        for (int r = 0; r < 4; ++r) {        // D: col=lane&15 (j), row=(lane>>4)*4+r (seg)
            feat_v[(size_t)(b0 + lg * 4 + r) * D + jt * 16 + ln15] = acc[r] + bvj;
        }
    }
}

// K3 (MFMA, single-pass full-Wu): UNCHANGED from R12/R16.
__global__ __launch_bounds__(1024, 4)
void k_attn_e_mfma(const float* __restrict__ ifeat, const float* __restrict__ Wu,
                   const float* __restrict__ feat_v, const float* __restrict__ we,
                   const int* __restrict__ seg_ids, float* __restrict__ e_out) {
    __shared__ __bf16 Bs[256 * 256];   // 128 KB; row j stride 512 B; byte ^= (j&7)<<4

    int tx = threadIdx.x;
    int lane = tx & 63;
    int w = tx >> 6;                   // 0..15
    int ln15 = lane & 15;
    int lg = lane >> 4;

    {
        int jl = tx >> 2, kh = tx & 3;
        const float* wp = Wu + (size_t)jl * D + kh * 64;
        char* rowp = (char*)Bs + jl * 512;
        int sw = (jl & 7) << 4;
#pragma unroll
        for (int q = 0; q < 8; ++q) {
            float4 b0 = *(const float4*)(wp + q * 8);
            float4 b1 = *(const float4*)(wp + q * 8 + 4);
            bf16x8 v;
            v[0] = (__bf16)b0.x; v[1] = (__bf16)b0.y; v[2] = (__bf16)b0.z; v[3] = (__bf16)b0.w;
            v[4] = (__bf16)b1.x; v[5] = (__bf16)b1.y; v[6] = (__bf16)b1.z; v[7] = (__bf16)b1.w;
            *(bf16x8*)(rowp + ((kh * 128 + q * 16) ^ sw)) = v;
        }
    }
    __syncthreads();

    int swr = (ln15 & 7) << 4;
    int klo = lg * 16;
    const char* bbase = (const char*)Bs + ln15 * 512;
    const float* feph = feat_v + ln15;
    const float* weh  = we + ln15;

    int wgid = blockIdx.x * 16 + w;

    for (int item = wgid; item < NN / 16; item += 4096) {
        int nb = item * 16;
        const float* ap = ifeat + (size_t)(nb + ln15) * D + lg * 8;

        f32x4 a0 = (f32x4){0.f,0.f,0.f,0.f}, a1 = a0, a2 = a0, a3 = a0,
              a4 = a0, a5 = a0, a6 = a0, a7 = a0,
              a8 = a0, a9 = a0, a10 = a0, a11 = a0,
              a12 = a0, a13 = a0, a14 = a0, a15 = a0;

        float4 xc = *(const float4*)(ap);
        float4 yc = *(const float4*)(ap + 4);
        float4 x1 = *(const float4*)(ap + 32);
        float4 y1 = *(const float4*)(ap + 36);
#pragma unroll 1
        for (int ch = 0; ch < 8; ++ch) {
            int nx = ((ch + 2) & 7) * 32;
            float4 x2 = *(const float4*)(ap + nx);
            float4 y2 = *(const float4*)(ap + nx + 4);
            bf16x8 af;
            af[0] = (__bf16)xc.x; af[1] = (__bf16)xc.y; af[2] = (__bf16)xc.z; af[3] = (__bf16)xc.w;
            af[4] = (__bf16)yc.x; af[5] = (__bf16)yc.y; af[6] = (__bf16)yc.z; af[7] = (__bf16)yc.w;
            int kb = (ch * 64 + klo) ^ swr;
            a0  = __builtin_amdgcn_mfma_f32_16x16x32_bf16(af, *(const bf16x8*)(bbase +  0 * 8192 + kb), a0,  0, 0, 0);
            a1  = __builtin_amdgcn_mfma_f32_16x16x32_bf16(af, *(const bf16x8*)(bbase +  1 * 8192 + kb), a1,  0, 0, 0);
            a2  = __builtin_amdgcn_mfma_f32_16x16x32_bf16(af, *(const bf16x8*)(bbase +  2 * 8192 + kb), a2,  0, 0, 0);
            a3  = __builtin_amdgcn_mfma_f32_16x16x32_bf16(af, *(const bf16x8*)(bbase +  3 * 8192 + kb), a3,  0, 0, 0);
            a4  = __builtin_amdgcn_mfma_f32_16x16x32_bf16(af, *(const bf16x8*)(bbase +  4 * 8192 + kb), a4,  0, 0, 0);
            a5  = __builtin_amdgcn_mfma_f32_16x16x32_bf16(af, *(const bf16x8*)(bbase +  5 * 8192 + kb), a5,  0, 0, 0);
            a6  = __builtin_amdgcn_mfma_f32_16x16x32_bf16(af, *(const bf16x8*)(bbase +  6 * 8192 + kb), a6,  0, 0, 0);
            a7  = __builtin_amdgcn_mfma_f32_16x16x32_bf16(af, *(const bf16x8*)(bbase +  7 * 8192 + kb), a7,  0, 0, 0);
            a8  = __builtin_amdgcn_mfma_f32_16x16x32_bf16(af, *(const bf16x8*)(bbase +  8 * 8192 + kb), a8,  0, 0, 0);
            a9  = __builtin_amdgcn_mfma_f32_16x16x32_bf16(af, *(const bf16x8*)(bbase +  9 * 8192 + kb), a9,  0, 0, 0);
            a10 = __builtin_amdgcn_mfma_f32_16x16x32_bf16(af, *(const bf16x8*)(bbase + 10 * 8192 + kb), a10, 0, 0, 0);
            a11 = __builtin_amdgcn_mfma_f32_16x16x32_bf16(af, *(const bf16x8*)(bbase + 11 * 8192 + kb), a11, 0, 0, 0);
            a12 = __builtin_amdgcn_mfma_f32_16x16x32_bf16(af, *(const bf16x8*)(bbase + 12 * 8192 + kb), a12, 0, 0, 0);
            a13 = __builtin_amdgcn_mfma_f32_16x16x32_bf16(af, *(const bf16x8*)(bbase + 13 * 8192 + kb), a13, 0, 0, 0);
            a14 = __builtin_amdgcn_mfma_f32_16x16x32_bf16(af, *(const bf16x8*)(bbase + 14 * 8192 + kb), a14, 0, 0, 0);
            a15 = __builtin_amdgcn_mfma_f32_16x16x32_bf16(af, *(const bf16x8*)(bbase + 15 * 8192 + kb), a15, 0, 0, 0);
            xc = x1; yc = y1; x1 = x2; y1 = y2;
        }

        int r0 = nb + lg * 4;
        const float* fp0 = feph + (size_t)seg_ids[r0 + 0] * D;
        const float* fp1 = feph + (size_t)seg_ids[r0 + 1] * D;
        const float* fp2 = feph + (size_t)seg_ids[r0 + 2] * D;
        const float* fp3 = feph + (size_t)seg_ids[r0 + 3] * D;
        float part0 = 0.f, part1 = 0.f, part2 = 0.f, part3 = 0.f;

#define EPI(AC, CT) { \
    float w_ = weh[(CT) * 16]; \
    part0 += w_ * __builtin_amdgcn_rcpf(1.f + __expf(-(AC[0] + fp0[(CT) * 16]))); \
    part1 += w_ * __builtin_amdgcn_rcpf(1.f + __expf(-(AC[1] + fp1[(CT) * 16]))); \
    part2 += w_ * __builtin_amdgcn_rcpf(1.f + __expf(-(AC[2] + fp2[(CT) * 16]))); \
    part3 += w_ * __builtin_amdgcn_rcpf(1.f + __expf(-(AC[3] + fp3[(CT) * 16]))); }

        EPI(a0, 0)  EPI(a1, 1)  EPI(a2, 2)  EPI(a3, 3)
        EPI(a4, 4)  EPI(a5, 5)  EPI(a6, 6)  EPI(a7, 7)
        EPI(a8, 8)  EPI(a9, 9)  EPI(a10, 10) EPI(a11, 11)
        EPI(a12, 12) EPI(a13, 13) EPI(a14, 14) EPI(a15, 15)
#undef EPI

#pragma unroll
        for (int off = 8; off >= 1; off >>= 1) {
            part0 += __shfl_xor(part0, off, 64);
            part1 += __shfl_xor(part1, off, 64);
            part2 += __shfl_xor(part2, off, 64);
            part3 += __shfl_xor(part3, off, 64);
        }
        if (ln15 == 0) {
            float4 o = make_float4(part0, part1, part2, part3);
            *(float4*)&e_out[r0] = o;
        }
    }
}

// K4: segment softmax + alpha-weighted segment sum -> out[:, 0:256]. UNCHANGED.
__global__ void k_softmax_rst(const float* __restrict__ ifeat, const int* __restrict__ seg_start,
                              const float* __restrict__ e, float* __restrict__ out) {
    int b = blockIdx.x;
    int t = threadIdx.x; // 256
    int w = t >> 6, l = t & 63;
    int s = seg_start[b], en = seg_start[b + 1];
    float m = -1e30f;
    for (int i = s + t; i < en; i += 256) m = fmaxf(m, e[i]);
#pragma unroll
    for (int off = 32; off >= 1; off >>= 1) m = fmaxf(m, __shfl_xor(m, off, 64));
    __shared__ float red[4];
    if ((t & 63) == 0) red[t >> 6] = m;
    __syncthreads();
    float mall = fmaxf(fmaxf(red[0], red[1]), fmaxf(red[2], red[3]));
    float dsum = 0.f;
    for (int i = s + t; i < en; i += 256) dsum += __expf(e[i] - mall);
#pragma unroll
    for (int off = 32; off >= 1; off >>= 1) dsum += __shfl_xor(dsum, off, 64);
    __shared__ float red2[4];
    if ((t & 63) == 0) red2[t >> 6] = dsum;
    __syncthreads();
    float denom = red2[0] + red2[1] + red2[2] + red2[3];
    float invd = (en > s) ? 1.0f / denom : 0.f;

    float4 acc = make_float4(0.f, 0.f, 0.f, 0.f);
    for (int i = s + w; i < en; i += 4) {
        float al = __expf(e[i] - mall) * invd;
        float4 v = *(const float4*)(ifeat + (size_t)i * D + l * 4);
        acc.x += v.x * al; acc.y += v.y * al; acc.z += v.z * al; acc.w += v.w * al;
    }
    __shared__ float red3[4][256];
    *(float4*)&red3[w][l * 4] = acc;
    __syncthreads();
    out[(size_t)b * 512 + t] = (red3[0][t] + red3[1][t]) + (red3[2][t] + red3[3][t]);
}

extern "C" void kernel_launch(void* const* d_in, const int* in_sizes, int n_in,
                              void* d_out, int out_size, void* d_ws, size_t ws_size,
                              hipStream_t stream) {
    const float* ifeat = (const float*)d_in[0];
    const float* Wu    = (const float*)d_in[1];
    const float* Wv    = (const float*)d_in[2];
    const float* bv    = (const float*)d_in[3];
    const float* we    = (const float*)d_in[4];
    const int*   seg   = (const int*)d_in[5];
    float* out = (float*)d_out;

    char* ws = (char*)d_ws;
    int*   seg_start = (int*)ws;                                        // (B+1) ints
    float* feat_v    = (float*)(ws + 16384);                            // B*D floats (2 MB)
    float* e_buf     = (float*)(ws + 16384 + (size_t)B * D * 4);        // NN floats (400 KB)
    float* anc_buf   = (float*)(ws + 16384 + (size_t)B * D * 4 + 512 * 1024); // B*D floats (2 MB)

    k_bounds<<<(B + 1 + 255) / 256, 256, 0, stream>>>(seg, seg_start);
    k_anchor3<<<B, 256, 0, stream>>>(ifeat, seg_start, out, anc_buf);
    k_featv3<<<B / 16, 256, 0, stream>>>(anc_buf, Wv, bv, feat_v);
    k_attn_e_mfma<<<256, 1024, 0, stream>>>(ifeat, Wu, feat_v, we, seg, e_buf);
    k_softmax_rst<<<B, 256, 0, stream>>>(ifeat, seg_start, e_buf, out);
}

// Round 18
// 107.529 us; speedup vs baseline: 1.4628x; 1.0002x over previous
//
#include <hip/hip_runtime.h>
#include <math.h>

#define NN 102400
#define D 256
#define B 2048

typedef __bf16 bf16x8 __attribute__((ext_vector_type(8)));
typedef float f32x4 __attribute__((ext_vector_type(4)));

// K1 (R18): anchor + own bounds. 2048 blocks x 4 waves (8/CU). Threads 0-1
// binary-search this block's [s,e); t0 writes seg_start[b] (b==B-1 t1 writes
// seg_start[B]) — kills the separate k_bounds launch (R12/R13 ledger: each
// launch boundary costs ~6-9us). Anchor loop unchanged from R17.
__global__ __launch_bounds__(256)
void k_anchor3(const float* __restrict__ ifeat, const int* __restrict__ seg,
               float* __restrict__ out, float* __restrict__ anc_buf,
               int* __restrict__ seg_start) {
    __shared__ int sb[2];
    int b = blockIdx.x;
    int t = threadIdx.x;
    if (t < 2) {
        int target = b + t;
        int lo = 0, hi = NN;
        while (lo < hi) { int mid = (lo + hi) >> 1; if (seg[mid] < target) lo = mid + 1; else hi = mid; }
        sb[t] = lo;
        if (t == 0) seg_start[b] = lo;
        if (t == 1 && b == B - 1) seg_start[B] = lo;
    }
    __syncthreads();
    int w = t >> 6, l = t & 63;
    int s = sb[0], e = sb[1];
    const float* bp = ifeat + (size_t)l * 4;
    float4 a0 = make_float4(0.f, 0.f, 0.f, 0.f), a1 = a0, a2 = a0, a3 = a0, a4 = a0, a5 = a0;
    int i = s + w;
    for (; i + 20 < e; i += 24) {   // 6 strided rows per batch per wave
        float4 v0 = *(const float4*)(bp + (size_t)(i +  0) * D);
        float4 v1 = *(const float4*)(bp + (size_t)(i +  4) * D);
        float4 v2 = *(const float4*)(bp + (size_t)(i +  8) * D);
        float4 v3 = *(const float4*)(bp + (size_t)(i + 12) * D);
        float4 v4 = *(const float4*)(bp + (size_t)(i + 16) * D);
        float4 v5 = *(const float4*)(bp + (size_t)(i + 20) * D);
        a0.x += v0.x; a0.y += v0.y; a0.z += v0.z; a0.w += v0.w;
        a1.x += v1.x; a1.y += v1.y; a1.z += v1.z; a1.w += v1.w;
        a2.x += v2.x; a2.y += v2.y; a2.z += v2.z; a2.w += v2.w;
        a3.x += v3.x; a3.y += v3.y; a3.z += v3.z; a3.w += v3.w;
        a4.x += v4.x; a4.y += v4.y; a4.z += v4.z; a4.w += v4.w;
        a5.x += v5.x; a5.y += v5.y; a5.z += v5.z; a5.w += v5.w;
    }
    for (; i < e; i += 4) {
        float4 v = *(const float4*)(bp + (size_t)i * D);
        a0.x += v.x; a0.y += v.y; a0.z += v.z; a0.w += v.w;
    }
    float4 acc = make_float4(((a0.x + a1.x) + (a2.x + a3.x)) + (a4.x + a5.x),
                             ((a0.y + a1.y) + (a2.y + a3.y)) + (a4.y + a5.y),
                             ((a0.z + a1.z) + (a2.z + a3.z)) + (a4.z + a5.z),
                             ((a0.w + a1.w) + (a2.w + a3.w)) + (a4.w + a5.w));
    __shared__ float red[4][256];
    *(float4*)&red[w][l * 4] = acc;
    __syncthreads();
    float sum = (red[0][t] + red[1][t]) + (red[2][t] + red[3][t]);
    int cnt = e - s;
    float inv = 1.0f / (float)(cnt > 0 ? cnt : 1);
    float v = sum * inv;
    out[(size_t)b * 512 + 256 + t] = v;
    anc_buf[(size_t)b * D + t] = v;
}

// K2 (MFMA featv): feat_v = anc @ Wv^T + bv. UNCHANGED from R17.
__global__ __launch_bounds__(256)
void k_featv3(const float* __restrict__ anc_buf, const float* __restrict__ Wv,
              const float* __restrict__ bv, float* __restrict__ feat_v) {
    __shared__ __bf16 As[16][264];   // 256 + 8 pad
    int b0 = blockIdx.x * 16;
    int t = threadIdx.x;
    int lane = t & 63, w = t >> 6;
    int ln15 = lane & 15, lg = lane >> 4;
#pragma unroll
    for (int r = 0; r < 16; ++r) As[r][t] = (__bf16)anc_buf[(size_t)(b0 + r) * D + t];
    __syncthreads();
    bf16x8 afr[8];
#pragma unroll
    for (int kc = 0; kc < 8; ++kc) afr[kc] = *(const bf16x8*)&As[ln15][kc * 32 + lg * 8];
#pragma unroll
    for (int q = 0; q < 4; ++q) {
        int jt = w * 4 + q;                  // 16 j-tiles over 4 waves
        f32x4 acc = (f32x4){0.f, 0.f, 0.f, 0.f};
#pragma unroll
        for (int kc = 0; kc < 8; ++kc) {
            const float* wp = Wv + (size_t)(jt * 16 + ln15) * D + kc * 32 + lg * 8;
            float4 p = *(const float4*)(wp);
            float4 r4 = *(const float4*)(wp + 4);
            bf16x8 bfr;
            bfr[0] = (__bf16)p.x;  bfr[1] = (__bf16)p.y;  bfr[2] = (__bf16)p.z;  bfr[3] = (__bf16)p.w;
            bfr[4] = (__bf16)r4.x; bfr[5] = (__bf16)r4.y; bfr[6] = (__bf16)r4.z; bfr[7] = (__bf16)r4.w;
            acc = __builtin_amdgcn_mfma_f32_16x16x32_bf16(afr[kc], bfr, acc, 0, 0, 0);
        }
        float bvj = bv[jt * 16 + ln15];
#pragma unroll
        for (int r = 0; r < 4; ++r) {
            feat_v[(size_t)(b0 + lg * 4 + r) * D + jt * 16 + ln15] = acc[r] + bvj;
        }
    }
}

// K3 (MFMA attn): R18 change: wgid = bid + 256*w (was bid*16+w). Old map put
// 2-item waves in blocks 0-143 only -> half the CUs idle for attn's 2nd half
// (wall 8 item-units/SIMD); new map spreads them over all blocks (wall 7).
// Everything else UNCHANGED from R12.
__global__ __launch_bounds__(1024, 4)
void k_attn_e_mfma(const float* __restrict__ ifeat, const float* __restrict__ Wu,
                   const float* __restrict__ feat_v, const float* __restrict__ we,
                   const int* __restrict__ seg_ids, float* __restrict__ e_out) {
    __shared__ __bf16 Bs[256 * 256];   // 128 KB; row j stride 512 B; byte ^= (j&7)<<4

    int tx = threadIdx.x;
    int lane = tx & 63;
    int w = tx >> 6;                   // 0..15
    int ln15 = lane & 15;
    int lg = lane >> 4;

    {
        int jl = tx >> 2, kh = tx & 3;
        const float* wp = Wu + (size_t)jl * D + kh * 64;
        char* rowp = (char*)Bs + jl * 512;
        int sw = (jl & 7) << 4;
#pragma unroll
        for (int q = 0; q < 8; ++q) {
            float4 b0 = *(const float4*)(wp + q * 8);
            float4 b1 = *(const float4*)(wp + q * 8 + 4);
            bf16x8 v;
            v[0] = (__bf16)b0.x; v[1] = (__bf16)b0.y; v[2] = (__bf16)b0.z; v[3] = (__bf16)b0.w;
            v[4] = (__bf16)b1.x; v[5] = (__bf16)b1.y; v[6] = (__bf16)b1.z; v[7] = (__bf16)b1.w;
            *(bf16x8*)(rowp + ((kh * 128 + q * 16) ^ sw)) = v;
        }
    }
    __syncthreads();

    int swr = (ln15 & 7) << 4;
    int klo = lg * 16;
    const char* bbase = (const char*)Bs + ln15 * 512;
    const float* feph = feat_v + ln15;
    const float* weh  = we + ln15;

    int wgid = blockIdx.x + 256 * w;         // R18: SIMD-balanced item map

    for (int item = wgid; item < NN / 16; item += 4096) {
        int nb = item * 16;
        const float* ap = ifeat + (size_t)(nb + ln15) * D + lg * 8;

        f32x4 a0 = (f32x4){0.f,0.f,0.f,0.f}, a1 = a0, a2 = a0, a3 = a0,
              a4 = a0, a5 = a0, a6 = a0, a7 = a0,
              a8 = a0, a9 = a0, a10 = a0, a11 = a0,
              a12 = a0, a13 = a0, a14 = a0, a15 = a0;

        float4 xc = *(const float4*)(ap);
        float4 yc = *(const float4*)(ap + 4);
        float4 x1 = *(const float4*)(ap + 32);
        float4 y1 = *(const float4*)(ap + 36);
#pragma unroll 1
        for (int ch = 0; ch < 8; ++ch) {
            int nx = ((ch + 2) & 7) * 32;
            float4 x2 = *(const float4*)(ap + nx);
            float4 y2 = *(const float4*)(ap + nx + 4);
            bf16x8 af;
            af[0] = (__bf16)xc.x; af[1] = (__bf16)xc.y; af[2] = (__bf16)xc.z; af[3] = (__bf16)xc.w;
            af[4] = (__bf16)yc.x; af[5] = (__bf16)yc.y; af[6] = (__bf16)yc.z; af[7] = (__bf16)yc.w;
            int kb = (ch * 64 + klo) ^ swr;
            a0  = __builtin_amdgcn_mfma_f32_16x16x32_bf16(af, *(const bf16x8*)(bbase +  0 * 8192 + kb), a0,  0, 0, 0);
            a1  = __builtin_amdgcn_mfma_f32_16x16x32_bf16(af, *(const bf16x8*)(bbase +  1 * 8192 + kb), a1,  0, 0, 0);
            a2  = __builtin_amdgcn_mfma_f32_16x16x32_bf16(af, *(const bf16x8*)(bbase +  2 * 8192 + kb), a2,  0, 0, 0);
            a3  = __builtin_amdgcn_mfma_f32_16x16x32_bf16(af, *(const bf16x8*)(bbase +  3 * 8192 + kb), a3,  0, 0, 0);
            a4  = __builtin_amdgcn_mfma_f32_16x16x32_bf16(af, *(const bf16x8*)(bbase +  4 * 8192 + kb), a4,  0, 0, 0);
            a5  = __builtin_amdgcn_mfma_f32_16x16x32_bf16(af, *(const bf16x8*)(bbase +  5 * 8192 + kb), a5,  0, 0, 0);
            a6  = __builtin_amdgcn_mfma_f32_16x16x32_bf16(af, *(const bf16x8*)(bbase +  6 * 8192 + kb), a6,  0, 0, 0);
            a7  = __builtin_amdgcn_mfma_f32_16x16x32_bf16(af, *(const bf16x8*)(bbase +  7 * 8192 + kb), a7,  0, 0, 0);
            a8  = __builtin_amdgcn_mfma_f32_16x16x32_bf16(af, *(const bf16x8*)(bbase +  8 * 8192 + kb), a8,  0, 0, 0);
            a9  = __builtin_amdgcn_mfma_f32_16x16x32_bf16(af, *(const bf16x8*)(bbase +  9 * 8192 + kb), a9,  0, 0, 0);
            a10 = __builtin_amdgcn_mfma_f32_16x16x32_bf16(af, *(const bf16x8*)(bbase + 10 * 8192 + kb), a10, 0, 0, 0);
            a11 = __builtin_amdgcn_mfma_f32_16x16x32_bf16(af, *(const bf16x8*)(bbase + 11 * 8192 + kb), a11, 0, 0, 0);
            a12 = __builtin_amdgcn_mfma_f32_16x16x32_bf16(af, *(const bf16x8*)(bbase + 12 * 8192 + kb), a12, 0, 0, 0);
            a13 = __builtin_amdgcn_mfma_f32_16x16x32_bf16(af, *(const bf16x8*)(bbase + 13 * 8192 + kb), a13, 0, 0, 0);
            a14 = __builtin_amdgcn_mfma_f32_16x16x32_bf16(af, *(const bf16x8*)(bbase + 14 * 8192 + kb), a14, 0, 0, 0);
            a15 = __builtin_amdgcn_mfma_f32_16x16x32_bf16(af, *(const bf16x8*)(bbase + 15 * 8192 + kb), a15, 0, 0, 0);
            xc = x1; yc = y1; x1 = x2; y1 = y2;
        }

        int r0 = nb + lg * 4;
        const float* fp0 = feph + (size_t)seg_ids[r0 + 0] * D;
        const float* fp1 = feph + (size_t)seg_ids[r0 + 1] * D;
        const float* fp2 = feph + (size_t)seg_ids[r0 + 2] * D;
        const float* fp3 = feph + (size_t)seg_ids[r0 + 3] * D;
        float part0 = 0.f, part1 = 0.f, part2 = 0.f, part3 = 0.f;

#define EPI(AC, CT) { \
    float w_ = weh[(CT) * 16]; \
    part0 += w_ * __builtin_amdgcn_rcpf(1.f + __expf(-(AC[0] + fp0[(CT) * 16]))); \
    part1 += w_ * __builtin_amdgcn_rcpf(1.f + __expf(-(AC[1] + fp1[(CT) * 16]))); \
    part2 += w_ * __builtin_amdgcn_rcpf(1.f + __expf(-(AC[2] + fp2[(CT) * 16]))); \
    part3 += w_ * __builtin_amdgcn_rcpf(1.f + __expf(-(AC[3] + fp3[(CT) * 16]))); }

        EPI(a0, 0)  EPI(a1, 1)  EPI(a2, 2)  EPI(a3, 3)
        EPI(a4, 4)  EPI(a5, 5)  EPI(a6, 6)  EPI(a7, 7)
        EPI(a8, 8)  EPI(a9, 9)  EPI(a10, 10) EPI(a11, 11)
        EPI(a12, 12) EPI(a13, 13) EPI(a14, 14) EPI(a15, 15)
#undef EPI

#pragma unroll
        for (int off = 8; off >= 1; off >>= 1) {
            part0 += __shfl_xor(part0, off, 64);
            part1 += __shfl_xor(part1, off, 64);
            part2 += __shfl_xor(part2, off, 64);
            part3 += __shfl_xor(part3, off, 64);
        }
        if (ln15 == 0) {
            float4 o = make_float4(part0, part1, part2, part3);
            *(float4*)&e_out[r0] = o;
        }
    }
}

// K4: segment softmax + alpha-weighted segment sum -> out[:, 0:256]. UNCHANGED.
__global__ void k_softmax_rst(const float* __restrict__ ifeat, const int* __restrict__ seg_start,
                              const float* __restrict__ e, float* __restrict__ out) {
    int b = blockIdx.x;
    int t = threadIdx.x; // 256
    int w = t >> 6, l = t & 63;
    int s = seg_start[b], en = seg_start[b + 1];
    float m = -1e30f;
    for (int i = s + t; i < en; i += 256) m = fmaxf(m, e[i]);
#pragma unroll
    for (int off = 32; off >= 1; off >>= 1) m = fmaxf(m, __shfl_xor(m, off, 64));
    __shared__ float red[4];
    if ((t & 63) == 0) red[t >> 6] = m;
    __syncthreads();
    float mall = fmaxf(fmaxf(red[0], red[1]), fmaxf(red[2], red[3]));
    float dsum = 0.f;
    for (int i = s + t; i < en; i += 256) dsum += __expf(e[i] - mall);
#pragma unroll
    for (int off = 32; off >= 1; off >>= 1) dsum += __shfl_xor(dsum, off, 64);
    __shared__ float red2[4];
    if ((t & 63) == 0) red2[t >> 6] = dsum;
    __syncthreads();
    float denom = red2[0] + red2[1] + red2[2] + red2[3];
    float invd = (en > s) ? 1.0f / denom : 0.f;

    float4 acc = make_float4(0.f, 0.f, 0.f, 0.f);
    for (int i = s + w; i < en; i += 4) {
        float al = __expf(e[i] - mall) * invd;
        float4 v = *(const float4*)(ifeat + (size_t)i * D + l * 4);
        acc.x += v.x * al; acc.y += v.y * al; acc.z += v.z * al; acc.w += v.w * al;
    }
    __shared__ float red3[4][256];
    *(float4*)&red3[w][l * 4] = acc;
    __syncthreads();
    out[(size_t)b * 512 + t] = (red3[0][t] + red3[1][t]) + (red3[2][t] + red3[3][t]);
}

extern "C" void kernel_launch(void* const* d_in, const int* in_sizes, int n_in,
                              void* d_out, int out_size, void* d_ws, size_t ws_size,
                              hipStream_t stream) {
    const float* ifeat = (const float*)d_in[0];
    const float* Wu    = (const float*)d_in[1];
    const float* Wv    = (const float*)d_in[2];
    const float* bv    = (const float*)d_in[3];
    const float* we    = (const float*)d_in[4];
    const int*   seg   = (const int*)d_in[5];
    float* out = (float*)d_out;

    char* ws = (char*)d_ws;
    int*   seg_start = (int*)ws;                                        // (B+1) ints
    float* feat_v    = (float*)(ws + 16384);                            // B*D floats (2 MB)
    float* e_buf     = (float*)(ws + 16384 + (size_t)B * D * 4);        // NN floats (400 KB)
    float* anc_buf   = (float*)(ws + 16384 + (size_t)B * D * 4 + 512 * 1024); // B*D floats (2 MB)

    k_anchor3<<<B, 256, 0, stream>>>(ifeat, seg, out, anc_buf, seg_start);
    k_featv3<<<B / 16, 256, 0, stream>>>(anc_buf, Wv, bv, feat_v);
    k_attn_e_mfma<<<256, 1024, 0, stream>>>(ifeat, Wu, feat_v, we, seg, e_buf);
    k_softmax_rst<<<B, 256, 0, stream>>>(ifeat, seg_start, e_buf, out);
}